// Round 11
// baseline (108.170 us; speedup 1.0000x reference)
//
#include <hip/hip_runtime.h>

#define NRAYS 8192
#define NS    256
#define HID   64
#define NPAIR 32     // hidden-unit pairs
#define NP4   16     // hidden-unit quads
#define RPB   4      // rays per block, one wave per ray
#define SPT   4      // samples per thread (64 lanes cover 256 samples)

typedef _Float16 f16x2 __attribute__((ext_vector_type(2)));

static __device__ __forceinline__ float fdot2(f16x2 a, f16x2 b, float c) {
    return __builtin_amdgcn_fdot2(a, b, c, false);   // v_dot2_f32_f16
}
static __device__ __forceinline__ f16x2 mk2(float a, float b) {
    f16x2 v; v.x = (_Float16)a; v.y = (_Float16)b; return v;
}

struct __align__(16) W4  { f16x2 ws, wr, wg, wb; };        // 16 B -> ds_read_b128
struct __align__(16) AB4 { f16x2 A01, B01, A23, B23; };    // 16 B -> ds_read_b128

__global__ __launch_bounds__(256, 8) void vr_kernel(
    const float* __restrict__ ray_start,
    const float* __restrict__ ray_dir,
    const float* __restrict__ sampled_depth,
    const float* __restrict__ sampled_dists,
    const int*   __restrict__ sampled_idx,
    const float* __restrict__ W1,
    const float* __restrict__ b1,
    const float* __restrict__ w_sigma,
    const float* __restrict__ W_rgb,
    const float* __restrict__ W_dir,
    const float* __restrict__ b_rgb,
    float* __restrict__ out)
{
    // sW[k]    : f16 pairs {w_sigma, W_rgb[:,c]} for hidden units 2k,2k+1
    // sAB[r][i]: f16 {A,B} for units 4i..4i+3, hv(h,d) = relu(A + d*B)
    __shared__ W4  sW[NPAIR];
    __shared__ AB4 sAB[RPB][NP4];

    const int t = threadIdx.x;
    if (t < NPAIR) {
        const int h0 = 2*t, h1 = 2*t + 1;
        W4 w;
        w.ws = mk2(w_sigma[h0],    w_sigma[h1]);
        w.wr = mk2(W_rgb[h0*3+0],  W_rgb[h1*3+0]);
        w.wg = mk2(W_rgb[h0*3+1],  W_rgb[h1*3+1]);
        w.wb = mk2(W_rgb[h0*3+2],  W_rgb[h1*3+2]);
        sW[t] = w;
    }
    {   // 256 threads = 4 rays x 64 h: one (ray, h) each
        const int rr  = t >> 6;
        const int h   = t & 63;
        const int ray = blockIdx.x * RPB + rr;
        const float ox = ray_start[ray*3+0], oy = ray_start[ray*3+1], oz = ray_start[ray*3+2];
        const float dx = ray_dir[ray*3+0],  dy = ray_dir[ray*3+1],  dz = ray_dir[ray*3+2];
        const float w0 = W1[h], w1 = W1[HID + h], w2 = W1[2*HID + h];
        const float A = fmaf(w0, ox, fmaf(w1, oy, fmaf(w2, oz, b1[h])));
        const float B = fmaf(w0, dx, fmaf(w1, dy, w2 * dz));
        // AB4 halfword layout: {A0,A1,B0,B1,A2,A3,B2,B3} for units 4i+m
        const int i = h >> 2, m = h & 3;
        _Float16* dst16 = (_Float16*)&sAB[rr][i];
        dst16[(m >> 1) * 4 + (m & 1)]     = (_Float16)A;
        dst16[(m >> 1) * 4 + (m & 1) + 2] = (_Float16)B;
    }
    __syncthreads();

    const int lane = t & 63;
    const int wv   = t >> 6;                 // wave = ray slot
    const int ray  = blockIdx.x * RPB + wv;

    // per-ray view-dependent rgb bias (fp32, wave-uniform)
    const float dx = ray_dir[ray*3+0], dy = ray_dir[ray*3+1], dz = ray_dir[ray*3+2];
    const float dwr = fmaf(dx, W_dir[0], fmaf(dy, W_dir[3], fmaf(dz, W_dir[6], b_rgb[0])));
    const float dwg = fmaf(dx, W_dir[1], fmaf(dy, W_dir[4], fmaf(dz, W_dir[7], b_rgb[1])));
    const float dwb = fmaf(dx, W_dir[2], fmaf(dy, W_dir[5], fmaf(dz, W_dir[8], b_rgb[2])));

    // this thread owns samples 4*lane .. 4*lane+3 (contiguous)
    const size_t rbase = (size_t)ray * NS + (size_t)lane * SPT;
    const float4 dep = *(const float4*)(sampled_depth + rbase);
    const float4 dst = *(const float4*)(sampled_dists + rbase);
    const int4  vidx = *(const int4*)(sampled_idx + rbase);

    const float dpt[SPT] = {dep.x, dep.y, dep.z, dep.w};
    const float dsv[SPT] = {dst.x, dst.y, dst.z, dst.w};
    const int   vid[SPT] = {vidx.x, vidx.y, vidx.z, vidx.w};

    f16x2 d2[SPT];
#pragma unroll
    for (int j = 0; j < SPT; ++j) d2[j] = mk2(dpt[j], dpt[j]);
    const f16x2 zero2 = mk2(0.f, 0.f);

    float sig[SPT] = {0,0,0,0};
    float cr[SPT]  = {0,0,0,0};
    float cg[SPT]  = {0,0,0,0};
    float cb[SPT]  = {0,0,0,0};

#pragma unroll 2
    for (int i = 0; i < NP4; ++i) {
        const W4  w0 = sW[2*i];        // ds_read_b128, broadcast
        const W4  w1 = sW[2*i + 1];    // ds_read_b128, broadcast
        const AB4 ab = sAB[wv][i];     // ds_read_b128, broadcast
#pragma unroll
        for (int j = 0; j < SPT; ++j) {
            f16x2 hv0 = __builtin_elementwise_fma(ab.B01, d2[j], ab.A01);  // v_pk_fma_f16
            f16x2 hv1 = __builtin_elementwise_fma(ab.B23, d2[j], ab.A23);
            hv0 = __builtin_elementwise_max(hv0, zero2);                   // v_pk_max_f16
            hv1 = __builtin_elementwise_max(hv1, zero2);
            sig[j] = fdot2(hv0, w0.ws, sig[j]);                            // v_dot2_f32_f16
            cr[j]  = fdot2(hv0, w0.wr, cr[j]);
            cg[j]  = fdot2(hv0, w0.wg, cg[j]);
            cb[j]  = fdot2(hv0, w0.wb, cb[j]);
            sig[j] = fdot2(hv1, w1.ws, sig[j]);
            cr[j]  = fdot2(hv1, w1.wr, cr[j]);
            cg[j]  = fdot2(hv1, w1.wg, cg[j]);
            cb[j]  = fdot2(hv1, w1.wb, cb[j]);
        }
    }

    // free energy + thread-local inclusive scan (fp32 throughout)
    float c[SPT];
    float run = 0.f;
#pragma unroll
    for (int j = 0; j < SPT; ++j) {
        float f = fmaxf(sig[j], 0.f) * dsv[j] * 7.0f;
        if (vid[j] == -1) f = 0.f;
        run += f;
        c[j] = run;
    }

    // wave-level (width 64) exclusive scan of per-thread totals
    float tot = run;
#pragma unroll
    for (int off = 1; off < 64; off <<= 1) {
        const float v = __shfl_up(tot, off, 64);
        if (lane >= off) tot += v;
    }
    const float base = tot - run;

    // telescoped probs: p[j] = exp(-(base+c[j-1])) - exp(-(base+c[j]))
    float Eprev = __expf(-base);
    float prob[SPT];
    float s0 = 0.f, s1 = 0.f, s2 = 0.f, s3 = 0.f, s4 = 0.f;
#pragma unroll
    for (int j = 0; j < SPT; ++j) {
        const float Ej = __expf(-(base + c[j]));
        const float p  = Eprev - Ej;
        Eprev = Ej;
        prob[j] = p;
        const float rr = __builtin_amdgcn_rcpf(1.f + __expf(-(cr[j] + dwr)));
        const float gg = __builtin_amdgcn_rcpf(1.f + __expf(-(cg[j] + dwg)));
        const float bb = __builtin_amdgcn_rcpf(1.f + __expf(-(cb[j] + dwb)));
        s0 += p;
        s1 = fmaf(dpt[j], p, s1);
        s2 = fmaf(rr, p, s2);
        s3 = fmaf(gg, p, s3);
        s4 = fmaf(bb, p, s4);
    }

    // wave reduction of the 5 sums
#pragma unroll
    for (int off = 32; off >= 1; off >>= 1) {
        s0 += __shfl_xor(s0, off, 64);
        s1 += __shfl_xor(s1, off, 64);
        s2 += __shfl_xor(s2, off, 64);
        s3 += __shfl_xor(s3, off, 64);
        s4 += __shfl_xor(s4, off, 64);
    }

    float* orow = out + (size_t)ray * (NS + 5);
#pragma unroll
    for (int j = 0; j < SPT; ++j)
        orow[5 + SPT*lane + j] = prob[j];

    if (lane == 0) {
        orow[0] = s2;          // r
        orow[1] = s3;          // g
        orow[2] = s4;          // b
        orow[3] = s1;          // depth
        orow[4] = 1.f - s0;    // missed
    }
}

extern "C" void kernel_launch(void* const* d_in, const int* in_sizes, int n_in,
                              void* d_out, int out_size, void* d_ws, size_t ws_size,
                              hipStream_t stream)
{
    vr_kernel<<<NRAYS / RPB, 256, 0, stream>>>(
        (const float*)d_in[0],   // ray_start
        (const float*)d_in[1],   // ray_dir
        (const float*)d_in[2],   // sampled_depth
        (const float*)d_in[3],   // sampled_dists
        (const int*)  d_in[4],   // sampled_idx
        (const float*)d_in[5],   // W1
        (const float*)d_in[6],   // b1
        (const float*)d_in[7],   // w_sigma
        (const float*)d_in[8],   // W_rgb
        (const float*)d_in[9],   // W_dir
        (const float*)d_in[10],  // b_rgb
        (float*)d_out);
}

// Round 12
// 104.655 us; speedup vs baseline: 1.0336x; 1.0336x over previous
//
#include <hip/hip_runtime.h>

#define NRAYS 8192
#define NS    256
#define HID   64
#define NPAIR 32     // hidden-unit pairs
#define NP4   16     // hidden-unit quads
#define RPB   8      // rays per block: 4 waves x 2 half-waves
#define SPT   8      // samples per thread (32 threads cover 256 samples)

typedef _Float16 f16x2 __attribute__((ext_vector_type(2)));

static __device__ __forceinline__ float fdot2(f16x2 a, f16x2 b, float c) {
    return __builtin_amdgcn_fdot2(a, b, c, false);   // v_dot2_f32_f16
}
static __device__ __forceinline__ f16x2 mk2(float a, float b) {
    f16x2 v; v.x = (_Float16)a; v.y = (_Float16)b; return v;
}

struct __align__(16) W4  { f16x2 ws, wr, wg, wb; };        // 16 B -> ds_read_b128
struct __align__(16) AB4 { f16x2 A01, B01, A23, B23; };    // 16 B -> ds_read_b128

__global__ __launch_bounds__(256, 4) void vr_kernel(
    const float* __restrict__ ray_start,
    const float* __restrict__ ray_dir,
    const float* __restrict__ sampled_depth,
    const float* __restrict__ sampled_dists,
    const int*   __restrict__ sampled_idx,
    const float* __restrict__ W1,
    const float* __restrict__ b1,
    const float* __restrict__ w_sigma,
    const float* __restrict__ W_rgb,
    const float* __restrict__ W_dir,
    const float* __restrict__ b_rgb,
    float* __restrict__ out)
{
    // sW[k]    : f16 pairs {w_sigma, W_rgb[:,c]} for hidden units 2k,2k+1
    // sAB[r][i]: f16 {A,B} for units 4i..4i+3, hv(h,d) = relu(A + d*B)
    __shared__ W4  sW[NPAIR];
    __shared__ AB4 sAB[RPB][NP4];

    const int t = threadIdx.x;
    if (t < NPAIR) {
        const int h0 = 2*t, h1 = 2*t + 1;
        W4 w;
        w.ws = mk2(w_sigma[h0],    w_sigma[h1]);
        w.wr = mk2(W_rgb[h0*3+0],  W_rgb[h1*3+0]);
        w.wg = mk2(W_rgb[h0*3+1],  W_rgb[h1*3+1]);
        w.wb = mk2(W_rgb[h0*3+2],  W_rgb[h1*3+2]);
        sW[t] = w;
    }
#pragma unroll
    for (int p = 0; p < 2; ++p) {       // 512 (ray,h) pairs over 256 threads
        const int idx = t + p * 256;
        const int rr  = idx >> 6;
        const int h   = idx & 63;
        const int ray = blockIdx.x * RPB + rr;
        const float ox = ray_start[ray*3+0], oy = ray_start[ray*3+1], oz = ray_start[ray*3+2];
        const float dx = ray_dir[ray*3+0],  dy = ray_dir[ray*3+1],  dz = ray_dir[ray*3+2];
        const float w0 = W1[h], w1 = W1[HID + h], w2 = W1[2*HID + h];
        const float A = fmaf(w0, ox, fmaf(w1, oy, fmaf(w2, oz, b1[h])));
        const float B = fmaf(w0, dx, fmaf(w1, dy, w2 * dz));
        // AB4 halfword layout: {A0,A1,B0,B1,A2,A3,B2,B3} for units 4i+m
        const int i = h >> 2, m = h & 3;
        _Float16* dst16 = (_Float16*)&sAB[rr][i];
        dst16[(m >> 1) * 4 + (m & 1)]     = (_Float16)A;
        dst16[(m >> 1) * 4 + (m & 1) + 2] = (_Float16)B;
    }
    __syncthreads();

    const int lane = t & 63;
    const int wave = t >> 6;
    const int hl   = lane & 31;                 // position within half-wave
    const int r    = wave * 2 + (lane >> 5);    // ray slot in block
    const int ray  = blockIdx.x * RPB + r;

    // per-ray view-dependent rgb bias (fp32, uniform across half-wave)
    const float dx = ray_dir[ray*3+0], dy = ray_dir[ray*3+1], dz = ray_dir[ray*3+2];
    const float dwr = fmaf(dx, W_dir[0], fmaf(dy, W_dir[3], fmaf(dz, W_dir[6], b_rgb[0])));
    const float dwg = fmaf(dx, W_dir[1], fmaf(dy, W_dir[4], fmaf(dz, W_dir[7], b_rgb[1])));
    const float dwb = fmaf(dx, W_dir[2], fmaf(dy, W_dir[5], fmaf(dz, W_dir[8], b_rgb[2])));

    // this thread owns samples SPT*hl .. SPT*hl+7 (contiguous)
    const size_t rbase = (size_t)ray * NS + (size_t)hl * SPT;
    const float4 dep0 = ((const float4*)(sampled_depth + rbase))[0];
    const float4 dep1 = ((const float4*)(sampled_depth + rbase))[1];
    const float4 dst0 = ((const float4*)(sampled_dists + rbase))[0];
    const float4 dst1 = ((const float4*)(sampled_dists + rbase))[1];
    const int4   vi0  = ((const int4*)(sampled_idx + rbase))[0];
    const int4   vi1  = ((const int4*)(sampled_idx + rbase))[1];

    const float dpt[SPT] = {dep0.x, dep0.y, dep0.z, dep0.w, dep1.x, dep1.y, dep1.z, dep1.w};
    const float dsv[SPT] = {dst0.x, dst0.y, dst0.z, dst0.w, dst1.x, dst1.y, dst1.z, dst1.w};
    const int   vid[SPT] = {vi0.x, vi0.y, vi0.z, vi0.w, vi1.x, vi1.y, vi1.z, vi1.w};

    f16x2 d2[SPT];
#pragma unroll
    for (int j = 0; j < SPT; ++j) d2[j] = mk2(dpt[j], dpt[j]);
    const f16x2 zero2 = mk2(0.f, 0.f);

    float sig[SPT] = {0,0,0,0,0,0,0,0};
    float cr[SPT]  = {0,0,0,0,0,0,0,0};
    float cg[SPT]  = {0,0,0,0,0,0,0,0};
    float cb[SPT]  = {0,0,0,0,0,0,0,0};

#pragma unroll 4
    for (int i = 0; i < NP4; ++i) {
        const W4  w0 = sW[2*i];        // ds_read_b128, broadcast
        const W4  w1 = sW[2*i + 1];    // ds_read_b128, broadcast
        const AB4 ab = sAB[r][i];      // ds_read_b128, 2 addrs/wave
#pragma unroll
        for (int j = 0; j < SPT; ++j) {
            f16x2 hv0 = __builtin_elementwise_fma(ab.B01, d2[j], ab.A01);  // v_pk_fma_f16
            f16x2 hv1 = __builtin_elementwise_fma(ab.B23, d2[j], ab.A23);
            hv0 = __builtin_elementwise_max(hv0, zero2);                   // v_pk_max_f16
            hv1 = __builtin_elementwise_max(hv1, zero2);
            sig[j] = fdot2(hv0, w0.ws, sig[j]);                            // v_dot2_f32_f16
            cr[j]  = fdot2(hv0, w0.wr, cr[j]);
            cg[j]  = fdot2(hv0, w0.wg, cg[j]);
            cb[j]  = fdot2(hv0, w0.wb, cb[j]);
            sig[j] = fdot2(hv1, w1.ws, sig[j]);
            cr[j]  = fdot2(hv1, w1.wr, cr[j]);
            cg[j]  = fdot2(hv1, w1.wg, cg[j]);
            cb[j]  = fdot2(hv1, w1.wb, cb[j]);
        }
    }

    // free energy + thread-local inclusive scan (fp32 throughout)
    float c[SPT];
    float run = 0.f;
#pragma unroll
    for (int j = 0; j < SPT; ++j) {
        float f = fmaxf(sig[j], 0.f) * dsv[j] * 7.0f;
        if (vid[j] == -1) f = 0.f;
        run += f;
        c[j] = run;
    }

    // half-wave (width 32) exclusive scan of per-thread totals
    float tot = run;
#pragma unroll
    for (int off = 1; off < 32; off <<= 1) {
        const float v = __shfl_up(tot, off, 32);
        if (hl >= off) tot += v;
    }
    const float base = tot - run;

    // telescoped probs: p[j] = exp(-(base+c[j-1])) - exp(-(base+c[j]))
    float Eprev = __expf(-base);
    float prob[SPT];
    float s0 = 0.f, s1 = 0.f, s2 = 0.f, s3 = 0.f, s4 = 0.f;
#pragma unroll
    for (int j = 0; j < SPT; ++j) {
        const float Ej = __expf(-(base + c[j]));
        const float p  = Eprev - Ej;
        Eprev = Ej;
        prob[j] = p;
        const float rr = __builtin_amdgcn_rcpf(1.f + __expf(-(cr[j] + dwr)));
        const float gg = __builtin_amdgcn_rcpf(1.f + __expf(-(cg[j] + dwg)));
        const float bb = __builtin_amdgcn_rcpf(1.f + __expf(-(cb[j] + dwb)));
        s0 += p;
        s1 = fmaf(dpt[j], p, s1);
        s2 = fmaf(rr, p, s2);
        s3 = fmaf(gg, p, s3);
        s4 = fmaf(bb, p, s4);
    }

    // store probs BEFORE the reduction: overlap store latency with shuffles
    float* orow = out + (size_t)ray * (NS + 5);
#pragma unroll
    for (int j = 0; j < SPT; ++j)
        orow[5 + SPT*hl + j] = prob[j];

    // half-wave reduction of the 5 sums
#pragma unroll
    for (int off = 16; off >= 1; off >>= 1) {
        s0 += __shfl_xor(s0, off, 32);
        s1 += __shfl_xor(s1, off, 32);
        s2 += __shfl_xor(s2, off, 32);
        s3 += __shfl_xor(s3, off, 32);
        s4 += __shfl_xor(s4, off, 32);
    }

    if (hl == 0) {
        orow[0] = s2;          // r
        orow[1] = s3;          // g
        orow[2] = s4;          // b
        orow[3] = s1;          // depth
        orow[4] = 1.f - s0;    // missed
    }
}

extern "C" void kernel_launch(void* const* d_in, const int* in_sizes, int n_in,
                              void* d_out, int out_size, void* d_ws, size_t ws_size,
                              hipStream_t stream)
{
    vr_kernel<<<NRAYS / RPB, 256, 0, stream>>>(
        (const float*)d_in[0],   // ray_start
        (const float*)d_in[1],   // ray_dir
        (const float*)d_in[2],   // sampled_depth
        (const float*)d_in[3],   // sampled_dists
        (const int*)  d_in[4],   // sampled_idx
        (const float*)d_in[5],   // W1
        (const float*)d_in[6],   // b1
        (const float*)d_in[7],   // w_sigma
        (const float*)d_in[8],   // W_rgb
        (const float*)d_in[9],   // W_dir
        (const float*)d_in[10],  // b_rgb
        (float*)d_out);
}